// Round 8
// baseline (344.498 us; speedup 1.0000x reference)
//
#include <hip/hip_runtime.h>
#include <hip/hip_bf16.h>
#include <stdint.h>

// ---------------------------------------------------------------------------
// MHA forward, B=2 S=2048 E=1024 H=16 D=64, fp32 in/out, bf16 MFMA internally.
// cvt+pack (flat balanced grid) -> QKV proj GEMM (z=3; z==2 writes V^T;
// coalesced LDS-bounced epilogues) -> flash attention (barrier-free main loop:
// kv-split across waves, direct L2-resident K/V fragment loads, fixed-m exp2
// softmax, den via ones-MFMA, LDS pair-reduction epilogue) -> out proj.
// ---------------------------------------------------------------------------

typedef __bf16 bf16x8 __attribute__((ext_vector_type(8)));
typedef __bf16 bf16x4 __attribute__((ext_vector_type(4)));
typedef float  f32x4  __attribute__((ext_vector_type(4)));
typedef unsigned int u32x4 __attribute__((ext_vector_type(4)));

#define MFMA16(a, b, c) __builtin_amdgcn_mfma_f32_16x16x32_bf16((a), (b), (c), 0, 0, 0)

#if __has_builtin(__builtin_amdgcn_exp2f)
#define EXP2(x) __builtin_amdgcn_exp2f(x)
#else
#define EXP2(x) exp2f(x)
#endif

static constexpr int kB = 2, kS = 2048, kE = 1024, kH = 16, kD = 64;
static constexpr int kM = kB * kS;                // 4096 rows
static constexpr int kMaskWordsPerRow = kS / 64;  // 32
static constexpr float kLog2e = 1.4426950408889634f;

// ---- async global->LDS (16B per lane, wave-uniform LDS base) --------------
__device__ __forceinline__ void gload_lds16(const void* g, void* l) {
  __builtin_amdgcn_global_load_lds(
      (const __attribute__((address_space(1))) unsigned int*)g,
      (__attribute__((address_space(3))) unsigned int*)l, 16, 0, 0);
}

__device__ __forceinline__ unsigned pack_bf16x2(float a, float b) {
  unsigned short lo = __builtin_bit_cast(unsigned short, (__bf16)a);
  unsigned short hi = __builtin_bit_cast(unsigned short, (__bf16)b);
  return (unsigned)lo | ((unsigned)hi << 16);
}

// ---------------------------------------------------------------------------
// Kernel 1: flat balanced grid.
// blocks [0,960): f32->bf16 of q,k,v (320 each, 2xfloat4 per iter)
// blocks [960,1216): weights Wq,Wk,Wv,Wo (64 each)
// blocks [1216,1664): mask bit-pack, 4 ballot words per wave-iter (MLP)
// ---------------------------------------------------------------------------
static constexpr int kCvtBlocks = 1664;

__global__ __launch_bounds__(256) void cvt_pack_kernel(
    const float* __restrict__ q, const float* __restrict__ k, const float* __restrict__ v,
    const float* __restrict__ wq, const float* __restrict__ wk,
    const float* __restrict__ wv, const float* __restrict__ wo,
    const int* __restrict__ mask,
    __bf16* __restrict__ qb, __bf16* __restrict__ kb, __bf16* __restrict__ vb,
    __bf16* __restrict__ wqb, __bf16* __restrict__ wkb,
    __bf16* __restrict__ wvb, __bf16* __restrict__ wob,
    unsigned long long* __restrict__ mw) {
  const int bid = blockIdx.x;
  if (bid < 1216) {
    const float* src; __bf16* dst; int n8, t0, stride;
    if (bid < 960) {
      const int seg = bid / 320, sb = bid - seg * 320;
      src = (seg == 0) ? q : (seg == 1) ? k : v;
      dst = (seg == 0) ? qb : (seg == 1) ? kb : vb;
      n8 = (kM * kE) >> 3;
      t0 = sb * 256 + threadIdx.x;
      stride = 320 * 256;
    } else {
      const int wseg = (bid - 960) >> 6, sb = (bid - 960) & 63;
      src = (wseg == 0) ? wq : (wseg == 1) ? wk : (wseg == 2) ? wv : wo;
      dst = (wseg == 0) ? wqb : (wseg == 1) ? wkb : (wseg == 2) ? wvb : wob;
      n8 = (kE * kE) >> 3;
      t0 = sb * 256 + threadIdx.x;
      stride = 64 * 256;
    }
    for (int i = t0; i < n8; i += stride) {
      float4 f0 = ((const float4*)src)[2 * i];
      float4 f1 = ((const float4*)src)[2 * i + 1];
      bf16x8 o = {(__bf16)f0.x, (__bf16)f0.y, (__bf16)f0.z, (__bf16)f0.w,
                  (__bf16)f1.x, (__bf16)f1.y, (__bf16)f1.z, (__bf16)f1.w};
      ((bf16x8*)dst)[i] = o;
    }
    return;
  }
  const int lane = threadIdx.x & 63;
  const int wid = ((bid - 1216) * 4 + (threadIdx.x >> 6));
  const int nwords = kB * kS * kMaskWordsPerRow;  // 131072
  const int stride4 = 1792 * 4;
  for (int w = wid * 4; w < nwords; w += stride4) {
    const int v0 = mask[(size_t)(w + 0) * 64 + lane];
    const int v1 = mask[(size_t)(w + 1) * 64 + lane];
    const int v2 = mask[(size_t)(w + 2) * 64 + lane];
    const int v3 = mask[(size_t)(w + 3) * 64 + lane];
    const unsigned long long b0 = __ballot(v0 != 0);
    const unsigned long long b1 = __ballot(v1 != 0);
    const unsigned long long b2 = __ballot(v2 != 0);
    const unsigned long long b3 = __ballot(v3 != 0);
    if (lane == 0) {
      ulonglong2 lo = {b0, b1}, hi = {b2, b3};
      *(ulonglong2*)&mw[w] = lo;
      *(ulonglong2*)&mw[w + 2] = hi;
    }
  }
}

// ---------------------------------------------------------------------------
// Kernel 2: C = A[4096,1024] @ W^T + bias (NT, bf16 MFMA), 128x128 tile.
// z=0: -> Qh [B,H,S,D] scaled by (1/8)*log2e; z=1: -> Kh [B,H,S,D];
// z=2: -> Vt [B,H,D,S]. All epilogues bounce through LDS for coalesced stores.
// ---------------------------------------------------------------------------
__global__ __launch_bounds__(256) void gemm_bt(
    const __bf16* __restrict__ A0, const __bf16* __restrict__ A1, const __bf16* __restrict__ A2,
    const __bf16* __restrict__ W0, const __bf16* __restrict__ W1, const __bf16* __restrict__ W2,
    const float* __restrict__ b0, const float* __restrict__ b1, const float* __restrict__ b2,
    __bf16* __restrict__ O0, __bf16* __restrict__ O1, __bf16* __restrict__ O2) {
  const int z = blockIdx.z;
  const __bf16* A = (z == 0) ? A0 : (z == 1) ? A1 : A2;
  const __bf16* W = (z == 0) ? W0 : (z == 1) ? W1 : W2;
  const float* bias = (z == 0) ? b0 : (z == 1) ? b1 : b2;
  __bf16* OutB = (z == 0) ? O0 : (z == 1) ? O1 : O2;
  const float scale = (z == 0) ? 0.125f * kLog2e : 1.0f;

  const int n0 = blockIdx.x * 128;
  const int m0 = blockIdx.y * 128;
  const int tid = threadIdx.x;
  const int wave = tid >> 6, lane = tid & 63;
  const int g = lane >> 4, qi = lane & 15;
  const int wm = wave >> 1, wn = wave & 1;

  __shared__ __align__(16) __bf16 As[128 * 32];
  __shared__ __align__(16) __bf16 Bs[128 * 32];
  __shared__ __align__(16) __bf16 Ts[128 * 72];  // epilogue bounce (both modes)

  f32x4 acc[4][4];
#pragma unroll
  for (int i = 0; i < 4; ++i)
#pragma unroll
    for (int jj = 0; jj < 4; ++jj) acc[i][jj] = (f32x4){0.f, 0.f, 0.f, 0.f};

  for (int k0 = 0; k0 < kE; k0 += 32) {
#pragma unroll
    for (int jj = 0; jj < 2; ++jj) {
      const int c = jj * 256 + tid;
      const int r = c >> 2, sl = c & 3;
      gload_lds16(&A[(size_t)(m0 + r) * kE + k0 + sl * 8], &As[c * 8]);
      gload_lds16(&W[(size_t)(n0 + r) * kE + k0 + sl * 8], &Bs[c * 8]);
    }
    __syncthreads();

    bf16x8 af[4], bfr[4];
#pragma unroll
    for (int mi = 0; mi < 4; ++mi)
      af[mi] = *(const bf16x8*)&As[(wm * 64 + mi * 16 + qi) * 32 + g * 8];
#pragma unroll
    for (int nj = 0; nj < 4; ++nj)
      bfr[nj] = *(const bf16x8*)&Bs[(wn * 64 + nj * 16 + qi) * 32 + g * 8];
#pragma unroll
    for (int mi = 0; mi < 4; ++mi)
#pragma unroll
      for (int nj = 0; nj < 4; ++nj)
        acc[mi][nj] = MFMA16(af[mi], bfr[nj], acc[mi][nj]);
    __syncthreads();
  }

  const int bb = m0 >> 11, ss0 = m0 & 2047;
  if (z == 2) {
    // transposed epilogue: Ts used as [64 d][136 s-stride]
#pragma unroll
    for (int half = 0; half < 2; ++half) {
      __syncthreads();
      if (wn == half) {
#pragma unroll
        for (int nj = 0; nj < 4; ++nj) {
          const int dl = nj * 16 + qi;
          const float bn = bias[n0 + half * 64 + dl];
#pragma unroll
          for (int mi = 0; mi < 4; ++mi) {
            const int srow = wm * 64 + mi * 16 + g * 4;
            bf16x4 o;
#pragma unroll
            for (int r = 0; r < 4; ++r) o[r] = (__bf16)(acc[mi][nj][r] + bn);
            *(bf16x4*)&Ts[dl * 136 + srow] = o;
          }
        }
      }
      __syncthreads();
      const int drow = tid >> 2, sc = (tid & 3) * 32;
      const int head = (n0 + half * 64) >> 6;
      __bf16* dst = OutB + (((size_t)bb * kH + head) * kD + drow) * kS + ss0 + sc;
#pragma unroll
      for (int jj = 0; jj < 4; ++jj) {
        bf16x8 vv = *(const bf16x8*)&Ts[drow * 136 + sc + jj * 8];
        *(bf16x8*)&dst[jj * 8] = vv;
      }
    }
    return;
  }

  // z<=1: row-major [B,H,S,D] epilogue via Ts [128 s][72] -> b128 stores
#pragma unroll
  for (int half = 0; half < 2; ++half) {
    __syncthreads();
    if (wn == half) {
#pragma unroll
      for (int nj = 0; nj < 4; ++nj) {
        const int dl = nj * 16 + qi;
        const float bn = bias[n0 + half * 64 + dl];
#pragma unroll
        for (int mi = 0; mi < 4; ++mi) {
          const int srow = wm * 64 + mi * 16 + g * 4;
#pragma unroll
          for (int r = 0; r < 4; ++r)
            Ts[(srow + r) * 72 + dl] = (__bf16)((acc[mi][nj][r] + bn) * scale);
        }
      }
    }
    __syncthreads();
    const int row = tid >> 1, cg = tid & 1;
    const int head = (n0 + half * 64) >> 6;
    __bf16* dst =
        OutB + (((size_t)bb * kH + head) * kS + ss0 + row) * kD + cg * 32;
#pragma unroll
    for (int jj = 0; jj < 4; ++jj)
      *(bf16x8*)&dst[jj * 8] = *(const bf16x8*)&Ts[row * 72 + cg * 32 + jj * 8];
  }
}

// ---------------------------------------------------------------------------
// Kernel 3: out projection, C = A[4096,1024] @ Wo^T + bo -> f32, 128x64 tile
// ---------------------------------------------------------------------------
__global__ __launch_bounds__(256) void gemm_out64(
    const __bf16* __restrict__ A, const __bf16* __restrict__ W,
    const float* __restrict__ bias, float* __restrict__ OF) {
  const int n0 = blockIdx.x * 64;
  const int m0 = blockIdx.y * 128;
  const int tid = threadIdx.x;
  const int wave = tid >> 6, lane = tid & 63;
  const int g = lane >> 4, qi = lane & 15;
  const int wm = wave >> 1, wn = wave & 1;

  __shared__ __align__(16) __bf16 As[128 * 32];
  __shared__ __align__(16) __bf16 Bs[64 * 32];

  f32x4 acc[4][2];
#pragma unroll
  for (int i = 0; i < 4; ++i)
#pragma unroll
    for (int jj = 0; jj < 2; ++jj) acc[i][jj] = (f32x4){0.f, 0.f, 0.f, 0.f};

  for (int k0 = 0; k0 < kE; k0 += 32) {
#pragma unroll
    for (int jj = 0; jj < 2; ++jj) {
      const int c = jj * 256 + tid;
      const int r = c >> 2, sl = c & 3;
      gload_lds16(&A[(size_t)(m0 + r) * kE + k0 + sl * 8], &As[c * 8]);
    }
    {
      const int r = tid >> 2, sl = tid & 3;
      gload_lds16(&W[(size_t)(n0 + r) * kE + k0 + sl * 8], &Bs[tid * 8]);
    }
    __syncthreads();

    bf16x8 af[4], bfr[2];
#pragma unroll
    for (int mi = 0; mi < 4; ++mi)
      af[mi] = *(const bf16x8*)&As[(wm * 64 + mi * 16 + qi) * 32 + g * 8];
#pragma unroll
    for (int nj = 0; nj < 2; ++nj)
      bfr[nj] = *(const bf16x8*)&Bs[(wn * 32 + nj * 16 + qi) * 32 + g * 8];
#pragma unroll
    for (int mi = 0; mi < 4; ++mi)
#pragma unroll
      for (int nj = 0; nj < 2; ++nj)
        acc[mi][nj] = MFMA16(af[mi], bfr[nj], acc[mi][nj]);
    __syncthreads();
  }

#pragma unroll
  for (int nj = 0; nj < 2; ++nj) {
    const int ncol = n0 + wn * 32 + nj * 16 + qi;
    const float bn = bias[ncol];
#pragma unroll
    for (int mi = 0; mi < 4; ++mi)
#pragma unroll
      for (int r = 0; r < 4; ++r) {
        const int mrow = m0 + wm * 64 + mi * 16 + g * 4 + r;
        OF[(size_t)mrow * kE + ncol] = acc[mi][nj][r] + bn;
      }
  }
}

// ---------------------------------------------------------------------------
// Kernel 4: flash attention, barrier-free main loop.
// Block = 4 waves = 2 q-groups (32 q-rows each) x 2 kv-halves (1024 each).
// Fixed-m softmax has no kv-sequential dependency -> waves run independent
// kv ranges; K/V fragments loaded directly from global (L2-resident 512KB/hd).
// Epilogue: kh=1 waves write partial acc/den to LDS, 1 barrier, kh=0 combine.
// Grid 1024 (4 blocks/CU), launch_bounds(256,4) -> 16 waves/CU.
// ---------------------------------------------------------------------------
__global__ __launch_bounds__(256, 4) void attn_kernel(
    const __bf16* __restrict__ Qh, const __bf16* __restrict__ Kh,
    const __bf16* __restrict__ Vt, const unsigned long long* __restrict__ mw,
    __bf16* __restrict__ Ob) {
  const int tid = threadIdx.x;
  const int wave = tid >> 6, lane = tid & 63;
  const int g = lane >> 4, qi = lane & 15;
  const int qg = wave >> 1, kh = wave & 1;
  // XCD swizzle: 1024 blocks; xcd = id%8 owns heads xcd*4..xcd*4+3.
  const int id = blockIdx.x;
  const int xcd = id & 7, j = id >> 3;       // j in [0,128)
  const int bh = xcd * 4 + (j >> 5);
  const int qb = j & 31;
  const int b = bh >> 4, h = bh & 15;

  const __bf16* Qp = Qh + (size_t)bh * kS * kD;
  const __bf16* Kp = Kh + (size_t)bh * kS * kD;
  const __bf16* Vp = Vt + (size_t)bh * kD * kS;

  const int q0 = qb * 64 + qg * 32 + qi;
  const int q1 = q0 + 16;
  const int kvbase = kh * 1024;
  const unsigned long long* M0 =
      mw + (size_t)(b * kS + q0) * kMaskWordsPerRow + kh * 16;
  const unsigned long long* M1 =
      mw + (size_t)(b * kS + q1) * kMaskWordsPerRow + kh * 16;

  // Q fragments (B-operand); (1/8)*log2e pre-folded into Qh.
  const bf16x8 qf00 = *(const bf16x8*)&Qp[(size_t)q0 * kD + g * 8];
  const bf16x8 qf01 = *(const bf16x8*)&Qp[(size_t)q0 * kD + 32 + g * 8];
  const bf16x8 qf10 = *(const bf16x8*)&Qp[(size_t)q1 * kD + g * 8];
  const bf16x8 qf11 = *(const bf16x8*)&Qp[(size_t)q1 * kD + 32 + g * 8];

  f32x4 acc0[4], acc1[4];
#pragma unroll
  for (int f = 0; f < 4; ++f) {
    acc0[f] = (f32x4){0.f, 0.f, 0.f, 0.f};
    acc1[f] = (f32x4){0.f, 0.f, 0.f, 0.f};
  }
  f32x4 accd0 = (f32x4){0.f, 0.f, 0.f, 0.f};
  f32x4 accd1 = (f32x4){0.f, 0.f, 0.f, 0.f};
  const f32x4 kZero = (f32x4){0.f, 0.f, 0.f, 0.f};
  const float ninf = __builtin_bit_cast(float, 0xff800000u);
  const u32x4 onesu = {0x3F803F80u, 0x3F803F80u, 0x3F803F80u, 0x3F803F80u};
  const bf16x8 vones = __builtin_bit_cast(bf16x8, onesu);

#pragma unroll 1
  for (int t = 0; t < 16; ++t) {
    const int kv0 = kvbase + t * 64;
    const unsigned long long w0_ = M0[t], w1_ = M1[t];
    unsigned wf0[4], wf1[4];
    {
      const unsigned lo0 = (unsigned)(w0_ >> (g * 4));
      const unsigned hi0 = (unsigned)(w0_ >> (32 + g * 4));
      wf0[0] = lo0; wf0[1] = lo0 >> 16; wf0[2] = hi0; wf0[3] = hi0 >> 16;
      const unsigned lo1 = (unsigned)(w1_ >> (g * 4));
      const unsigned hi1 = (unsigned)(w1_ >> (32 + g * 4));
      wf1[0] = lo1; wf1[1] = lo1 >> 16; wf1[2] = hi1; wf1[3] = hi1 >> 16;
    }

    // ---- QK^T (swapped): p[kv 16][q], masked to -inf ----
    float p0[16], p1[16];
    __builtin_amdgcn_s_setprio(1);
#pragma unroll
    for (int f = 0; f < 4; ++f) {
      const __bf16* kr = &Kp[(size_t)(kv0 + f * 16 + qi) * kD];
      const bf16x8 k0_ = *(const bf16x8*)&kr[g * 8];
      const bf16x8 k1_ = *(const bf16x8*)&kr[32 + g * 8];
      f32x4 st0 = MFMA16(k0_, qf00, kZero);
      st0 = MFMA16(k1_, qf01, st0);
      f32x4 st1 = MFMA16(k0_, qf10, kZero);
      st1 = MFMA16(k1_, qf11, st1);
#pragma unroll
      for (int r4 = 0; r4 < 4; ++r4) {
        p0[4 * f + r4] = (wf0[f] & (1u << r4)) ? st0[r4] : ninf;
        p1[4 * f + r4] = (wf1[f] & (1u << r4)) ? st1[r4] : ninf;
      }
    }
    __builtin_amdgcn_s_setprio(0);

    // ---- exp2 (fixed m=0; masked -> exp2(-inf)=0) ----
#pragma unroll
    for (int i = 0; i < 16; ++i) {
      p0[i] = EXP2(p0[i]);
      p1[i] = EXP2(p1[i]);
    }

    // ---- P -> bf16 PV B-fragments via cross-lane shuffle, then PV ----
    unsigned pk0[4][2], pk1[4][2];
#pragma unroll
    for (int f = 0; f < 4; ++f) {
      pk0[f][0] = pack_bf16x2(p0[4 * f + 0], p0[4 * f + 1]);
      pk0[f][1] = pack_bf16x2(p0[4 * f + 2], p0[4 * f + 3]);
      pk1[f][0] = pack_bf16x2(p1[4 * f + 0], p1[4 * f + 1]);
      pk1[f][1] = pack_bf16x2(p1[4 * f + 2], p1[4 * f + 3]);
    }
#pragma unroll
    for (int c = 0; c < 2; ++c) {
      unsigned bw0[4], bw1[4];
#pragma unroll
      for (int t4 = 0; t4 < 4; ++t4) {
        const int src_ = qi + 16 * ((t4 >> 1) + 2 * (g & 1));
        const int a0_ = __shfl((int)pk0[2 * c + 0][t4 & 1], src_);
        const int b0_ = __shfl((int)pk0[2 * c + 1][t4 & 1], src_);
        bw0[t4] = (g >= 2) ? (unsigned)b0_ : (unsigned)a0_;
        const int a1_ = __shfl((int)pk1[2 * c + 0][t4 & 1], src_);
        const int b1_ = __shfl((int)pk1[2 * c + 1][t4 & 1], src_);
        bw1[t4] = (g >= 2) ? (unsigned)b1_ : (unsigned)a1_;
      }
      const u32x4 u0_ = {bw0[0], bw0[1], bw0[2], bw0[3]};
      const u32x4 u1_ = {bw1[0], bw1[1], bw1[2], bw1[3]};
      const bf16x8 pb0 = __builtin_bit_cast(bf16x8, u0_);
      const bf16x8 pb1 = __builtin_bit_cast(bf16x8, u1_);
      __builtin_amdgcn_s_setprio(1);
#pragma unroll
      for (int f = 0; f < 4; ++f) {
        const bf16x8 vf_ =
            *(const bf16x8*)&Vp[(size_t)(f * 16 + qi) * kS + kv0 + c * 32 + g * 8];
        acc0[f] = MFMA16(vf_, pb0, acc0[f]);
        acc1[f] = MFMA16(vf_, pb1, acc1[f]);
      }
      accd0 = MFMA16(vones, pb0, accd0);
      accd1 = MFMA16(vones, pb1, accd1);
      __builtin_amdgcn_s_setprio(0);
    }
  }

  // ---- cross-wave pair reduction (kv halves) ----
  __shared__ float rbuf[2][64][33];
  __shared__ float rden[2][32];
  if (kh == 1) {
#pragma unroll
    for (int f = 0; f < 4; ++f)
#pragma unroll
      for (int r = 0; r < 4; ++r) {
        const int d = f * 16 + g * 4 + r;
        rbuf[qg][d][qi] = acc0[f][r];
        rbuf[qg][d][16 + qi] = acc1[f][r];
      }
    if (g == 0) {
      rden[qg][qi] = accd0[0];
      rden[qg][16 + qi] = accd1[0];
    }
  }
  __syncthreads();
  if (kh == 0) {
    const float ri0 = 1.0f / (accd0[0] + rden[qg][qi]);
    const float ri1 = 1.0f / (accd1[0] + rden[qg][16 + qi]);
    __bf16* Op0 = Ob + (size_t)(b * kS + q0) * kE + h * kD;
    __bf16* Op1 = Ob + (size_t)(b * kS + q1) * kE + h * kD;
#pragma unroll
    for (int f = 0; f < 4; ++f) {
      ushort4 o0, o1;
#pragma unroll
      for (int r = 0; r < 4; ++r) {
        const int d = f * 16 + g * 4 + r;
        const float v0 = (acc0[f][r] + rbuf[qg][d][qi]) * ri0;
        const float v1 = (acc1[f][r] + rbuf[qg][d][16 + qi]) * ri1;
        ((unsigned short*)&o0)[r] = __builtin_bit_cast(unsigned short, (__bf16)v0);
        ((unsigned short*)&o1)[r] = __builtin_bit_cast(unsigned short, (__bf16)v1);
      }
      *(ushort4*)&Op0[f * 16 + g * 4] = o0;
      *(ushort4*)&Op1[f * 16 + g * 4] = o1;
    }
  }
}

// ---------------------------------------------------------------------------
extern "C" void kernel_launch(void* const* d_in, const int* in_sizes, int n_in,
                              void* d_out, int out_size, void* d_ws, size_t ws_size,
                              hipStream_t stream) {
  (void)in_sizes; (void)n_in; (void)out_size; (void)ws_size;
  const float* q  = (const float*)d_in[0];
  const float* k  = (const float*)d_in[1];
  const float* v  = (const float*)d_in[2];
  const int*   mask = (const int*)d_in[3];
  const float* Wq = (const float*)d_in[4];
  const float* bq = (const float*)d_in[5];
  const float* Wk = (const float*)d_in[6];
  const float* bk = (const float*)d_in[7];
  const float* Wv = (const float*)d_in[8];
  const float* bv = (const float*)d_in[9];
  const float* Wo = (const float*)d_in[10];
  const float* bo = (const float*)d_in[11];

  char* ws = (char*)d_ws;
  const size_t MB = 1024 * 1024;
  __bf16* qb  = (__bf16*)(ws + 0 * MB);    // 8MB  [4096,1024]
  __bf16* kb  = (__bf16*)(ws + 8 * MB);    // 8MB
  __bf16* vb  = (__bf16*)(ws + 16 * MB);   // 8MB
  __bf16* wqb = (__bf16*)(ws + 24 * MB);   // 2MB
  __bf16* wkb = (__bf16*)(ws + 26 * MB);   // 2MB
  __bf16* wvb = (__bf16*)(ws + 28 * MB);   // 2MB
  __bf16* wob = (__bf16*)(ws + 30 * MB);   // 2MB
  __bf16* Qh  = (__bf16*)(ws + 32 * MB);   // 8MB [B,H,S,D]
  __bf16* Kh  = (__bf16*)(ws + 40 * MB);   // 8MB [B,H,S,D]
  __bf16* Vt  = (__bf16*)(ws + 48 * MB);   // 8MB [B,H,D,S]
  unsigned long long* mwords = (unsigned long long*)(ws + 56 * MB);  // 1MB
  __bf16* Ob = qb;   // qb dead after QKV GEMM

  cvt_pack_kernel<<<kCvtBlocks, 256, 0, stream>>>(
      q, k, v, Wq, Wk, Wv, Wo, mask, qb, kb, vb, wqb, wkb, wvb, wob, mwords);
  gemm_bt<<<dim3(8, 32, 3), 256, 0, stream>>>(qb, kb, vb, wqb, wkb, wvb,
                                              bq, bk, bv, Qh, Kh, Vt);
  attn_kernel<<<1024, 256, 0, stream>>>(Qh, Kh, Vt, mwords, Ob);
  gemm_out64<<<dim3(16, 32), 256, 0, stream>>>(Ob, wob, bo, (float*)d_out);
}